// Round 5
// baseline (731.690 us; speedup 1.0000x reference)
//
#include <hip/hip_runtime.h>

typedef __bf16 bf16x8 __attribute__((ext_vector_type(8)));
typedef float f32x4 __attribute__((ext_vector_type(4)));
typedef unsigned short ushort8 __attribute__((ext_vector_type(8)));
typedef unsigned int uu2 __attribute__((ext_vector_type(2)));

#define LDS_AS(p) ((__attribute__((address_space(3))) void*)(p))
#define GLB_AS(p) ((const __attribute__((address_space(1))) void*)(p))

__device__ __forceinline__ unsigned short f2bf(float f) {
    union { float f; unsigned u; } v; v.f = f;
    unsigned r = v.u + 0x7fffu + ((v.u >> 16) & 1u);
    return (unsigned short)(r >> 16);
}

// ---------------- weight fp32 -> bf16 conversion ----------------
__global__ __launch_bounds__(256) void convw_kernel(
    const float* __restrict__ wi, const float* __restrict__ wo,
    unsigned short* __restrict__ qw, unsigned short* __restrict__ ow)
{
    const int i = blockIdx.x * 256 + threadIdx.x;
    if (i < 1152 * 384) qw[i] = f2bf(wi[i]);
    if (i < 384 * 384)  ow[i] = f2bf(wo[i]);
}

// ---------------- LayerNorm + window partition + bf16 cast ----------------
__global__ __launch_bounds__(256) void ln_kernel(
    const float* __restrict__ x, const float* __restrict__ gam,
    const float* __restrict__ bet, unsigned short* __restrict__ y)
{
    const int lane = threadIdx.x & 63;
    const int wv   = threadIdx.x >> 6;
    const int m    = blockIdx.x * 4 + wv;
    const int win  = m / 49, l = m - win * 49;
    const int b = win >> 6, wh = (win >> 3) & 7, ww = win & 7;
    const int i = l / 7, j = l - i * 7;
    const float2* xr = (const float2*)(x + ((size_t)b * 3136 + (wh * 7 + i) * 56 + (ww * 7 + j)) * 384);

    float2 v[3];
    float s = 0.f, ss = 0.f;
#pragma unroll
    for (int t = 0; t < 3; ++t) {
        v[t] = xr[t * 64 + lane];
        s  += v[t].x + v[t].y;
        ss += v[t].x * v[t].x + v[t].y * v[t].y;
    }
#pragma unroll
    for (int d = 1; d < 64; d <<= 1) {
        s  += __shfl_xor(s, d, 64);
        ss += __shfl_xor(ss, d, 64);
    }
    const float mu  = s * (1.f / 384.f);
    const float var = ss * (1.f / 384.f) - mu * mu;
    const float rs  = rsqrtf(var + 1e-5f);

    unsigned* yr = (unsigned*)(y + (size_t)m * 384);
#pragma unroll
    for (int t = 0; t < 3; ++t) {
        const int c = (t * 64 + lane) * 2;
        float a0 = (v[t].x - mu) * rs * gam[c]     + bet[c];
        float a1 = (v[t].y - mu) * rs * gam[c + 1] + bet[c + 1];
        yr[t * 64 + lane] = (unsigned)f2bf(a0) | ((unsigned)f2bf(a1) << 16);
    }
}

// ---------------- 128x128 bf16 MFMA GEMM (QKV projection), K=384, BK=32 ----------------
// R5: verbatim R2 structure (best measured: 166 us, FETCH 42 MB, 0 conflicts).
// 3-buffer counted-vmcnt pipeline, T2 LDS swizzle, XCD-chunked grid swizzle,
// swapped-operand MFMA + vectorized bf16 store.
__global__ __launch_bounds__(256) void gemm_qkv_kernel(
    const unsigned short* __restrict__ A,
    const unsigned short* __restrict__ Bw,
    const float* __restrict__ bias,
    unsigned short* __restrict__ obf)
{
    __shared__ unsigned short As[3][128 * 32];
    __shared__ unsigned short Bs[3][128 * 32];
    const int lane = threadIdx.x & 63;
    const int wv   = threadIdx.x >> 6;

    const int NB = 9;   // 1152 / 128
    int sw = blockIdx.x;
    if ((gridDim.x & 7) == 0)
        sw = (sw & 7) * (int)(gridDim.x >> 3) + (sw >> 3);
    const int my = sw / NB;
    const int m0 = my * 128;
    const int n0 = (sw - my * NB) * 128;

    const int wm = (wv & 1) * 64;
    const int wn = (wv >> 1) * 64;
    const int cl = lane & 15;
    const int qd = lane >> 4;
    const int srow = wv * 16 + (lane >> 2);                      // staging row (+t*64)
    const int scol = ((lane & 3) ^ ((lane >> 3) & 3)) * 8;       // swizzled source chunk
    const int rc   = (qd ^ ((cl >> 1) & 3)) * 8;                 // swizzled read chunk

    const unsigned short* gA = A  + (size_t)(m0 + srow) * 384 + scol;
    const unsigned short* gB = Bw + (size_t)(n0 + srow) * 384 + scol;

    f32x4 acc[4][4] = {};

#define STAGE(BUF, KB) do {                                                                                   \
    __builtin_amdgcn_global_load_lds(GLB_AS(gA + (KB) * 32),            LDS_AS(&As[BUF][(wv * 16) * 32]),      16, 0, 0); \
    __builtin_amdgcn_global_load_lds(GLB_AS(gA + 64 * 384 + (KB) * 32), LDS_AS(&As[BUF][(64 + wv * 16) * 32]), 16, 0, 0); \
    __builtin_amdgcn_global_load_lds(GLB_AS(gB + (KB) * 32),            LDS_AS(&Bs[BUF][(wv * 16) * 32]),      16, 0, 0); \
    __builtin_amdgcn_global_load_lds(GLB_AS(gB + 64 * 384 + (KB) * 32), LDS_AS(&Bs[BUF][(64 + wv * 16) * 32]), 16, 0, 0); \
  } while (0)

    STAGE(0, 0);
    STAGE(1, 1);

#pragma unroll
    for (int kb = 0; kb < 12; ++kb) {
        const int cur = kb % 3;
        if (kb < 11) asm volatile("s_waitcnt vmcnt(4)\n\ts_barrier" ::: "memory");
        else         asm volatile("s_waitcnt vmcnt(0)\n\ts_barrier" ::: "memory");

        if (kb < 10) STAGE((kb + 2) % 3, kb + 2);

        bf16x8 af[4], bfr[4];
#pragma unroll
        for (int mt = 0; mt < 4; ++mt)
            af[mt] = *(const bf16x8*)(&As[cur][(wm + mt * 16 + cl) * 32 + rc]);
#pragma unroll
        for (int nt = 0; nt < 4; ++nt)
            bfr[nt] = *(const bf16x8*)(&Bs[cur][(wn + nt * 16 + cl) * 32 + rc]);
#pragma unroll
        for (int mt = 0; mt < 4; ++mt)
#pragma unroll
            for (int nt = 0; nt < 4; ++nt)   // swapped operands: lane cl -> m, qd*4+r -> n
                acc[mt][nt] = __builtin_amdgcn_mfma_f32_16x16x32_bf16(bfr[nt], af[mt], acc[mt][nt], 0, 0, 0);
    }
#undef STAGE

#pragma unroll
    for (int mt = 0; mt < 4; ++mt) {
        const int m = m0 + wm + mt * 16 + cl;
#pragma unroll
        for (int nt = 0; nt < 4; ++nt) {
            const int nb = n0 + wn + nt * 16 + qd * 4;
            const f32x4 bv = *(const f32x4*)(bias + nb);
            uu2 p;
            p[0] = (unsigned)f2bf(acc[mt][nt][0] + bv[0]) |
                   ((unsigned)f2bf(acc[mt][nt][1] + bv[1]) << 16);
            p[1] = (unsigned)f2bf(acc[mt][nt][2] + bv[2]) |
                   ((unsigned)f2bf(acc[mt][nt][3] + bv[3]) << 16);
            *(uu2*)(obf + (size_t)m * 1152 + nb) = p;
        }
    }
}

// ---------------- fused attention + out-proj + residual ----------------
// One block per window (4 waves). Phase A: each wave computes 3 heads of
// attention, O-slices -> LDS Otile (49 rows, stride 392 elems => 2-way bank
// aliasing only). Phase B: 49x384 GEMM vs w_out^T read straight from L2
// (294 KB, resident: every block reads it), swapped-operand MFMA, residual +
// fp32 store. Kills the owin HBM round-trip and the standalone gemm2 launch.
// Otile rows 49..63 are never written; phase-B reads of them land in the dead
// P-scratch region (in-bounds LDS) and are discarded by the l<49 store guard.
#define OT_STRIDE 392
__global__ __launch_bounds__(256) void attn_out_kernel(
    const unsigned short* __restrict__ qkv,
    const unsigned short* __restrict__ wout,
    const float* __restrict__ bias,
    const float* __restrict__ xres,
    float* __restrict__ out)
{
    __shared__ unsigned short OT[49 * OT_STRIDE];   // 38.4 KB
    __shared__ unsigned short P[4][64 * 72];        // 36.9 KB per-wave scratch
    const int lane = threadIdx.x & 63;
    const int wv   = threadIdx.x >> 6;
    const int cl = lane & 15;
    const int qd = lane >> 4;
    const int win = blockIdx.x;
    const unsigned short* base = qkv + (size_t)win * (49 * 1152);
    unsigned short* Pw = &P[wv][0];

    // ---------------- Phase A: attention, 3 heads per wave ----------------
    for (int rep = 0; rep < 3; ++rep) {
        const int h = wv * 3 + rep;

        // S = Q @ K^T  (64x64 padded, K=32)
        bf16x8 aq[4], bk[4];
#pragma unroll
        for (int mt = 0; mt < 4; ++mt) {
            const int l = mt * 16 + cl;
            bf16x8 z = {};
            if (l < 49) z = *(const bf16x8*)(base + (size_t)l * 1152 + h * 32 + qd * 8);
            aq[mt] = z;
        }
#pragma unroll
        for (int nt = 0; nt < 4; ++nt) {
            const int lk = nt * 16 + cl;
            bf16x8 z = {};
            if (lk < 49) z = *(const bf16x8*)(base + (size_t)lk * 1152 + 384 + h * 32 + qd * 8);
            bk[nt] = z;
        }
        f32x4 s[4][4] = {};
#pragma unroll
        for (int mt = 0; mt < 4; ++mt)
#pragma unroll
            for (int nt = 0; nt < 4; ++nt)
                s[mt][nt] = __builtin_amdgcn_mfma_f32_16x16x32_bf16(aq[mt], bk[nt], s[mt][nt], 0, 0, 0);

        const float scale = 0.17677669529663687f;   // 1/sqrt(32)
#pragma unroll
        for (int mt = 0; mt < 4; ++mt)
#pragma unroll
            for (int nt = 0; nt < 4; ++nt)
#pragma unroll
                for (int r = 0; r < 4; ++r) {
                    float t = s[mt][nt][r] * scale;
                    if (nt * 16 + cl >= 49) t = -1e30f;
                    s[mt][nt][r] = t;
                }

        // softmax over rows
#pragma unroll
        for (int mt = 0; mt < 4; ++mt)
#pragma unroll
            for (int r = 0; r < 4; ++r) {
                float mx = fmaxf(fmaxf(s[mt][0][r], s[mt][1][r]), fmaxf(s[mt][2][r], s[mt][3][r]));
                mx = fmaxf(mx, __shfl_xor(mx, 1, 64));
                mx = fmaxf(mx, __shfl_xor(mx, 2, 64));
                mx = fmaxf(mx, __shfl_xor(mx, 4, 64));
                mx = fmaxf(mx, __shfl_xor(mx, 8, 64));
                float sm = 0.f;
#pragma unroll
                for (int nt = 0; nt < 4; ++nt) {
                    const float p = __expf(s[mt][nt][r] - mx);
                    s[mt][nt][r] = p;
                    sm += p;
                }
                sm += __shfl_xor(sm, 1, 64);
                sm += __shfl_xor(sm, 2, 64);
                sm += __shfl_xor(sm, 4, 64);
                sm += __shfl_xor(sm, 8, 64);
                const float inv = 1.f / sm;
#pragma unroll
                for (int nt = 0; nt < 4; ++nt)
                    s[mt][nt][r] *= inv;
            }

        // P -> LDS (C-layout scatter), read back in A-layout
#pragma unroll
        for (int mt = 0; mt < 4; ++mt)
#pragma unroll
            for (int nt = 0; nt < 4; ++nt)
#pragma unroll
                for (int r = 0; r < 4; ++r)
                    Pw[(mt * 16 + qd * 4 + r) * 72 + nt * 16 + cl] = f2bf(s[mt][nt][r]);

        // O = P @ V   (64x32, K=64)
        f32x4 oa[4][2] = {};
        const unsigned short* vbase = base + 768 + h * 32;
#pragma unroll
        for (int kk = 0; kk < 2; ++kk) {
            bf16x8 ap[4];
#pragma unroll
            for (int mt = 0; mt < 4; ++mt)
                ap[mt] = *(const bf16x8*)(Pw + (mt * 16 + cl) * 72 + kk * 32 + qd * 8);
#pragma unroll
            for (int nt = 0; nt < 2; ++nt) {
                ushort8 tv;
#pragma unroll
                for (int jj = 0; jj < 8; ++jj) {
                    const int lk = kk * 32 + qd * 8 + jj;
                    tv[jj] = (lk < 49) ? vbase[(size_t)lk * 1152 + nt * 16 + cl] : (unsigned short)0;
                }
                const bf16x8 bv = __builtin_bit_cast(bf16x8, tv);
#pragma unroll
                for (int mt = 0; mt < 4; ++mt)
                    oa[mt][nt] = __builtin_amdgcn_mfma_f32_16x16x32_bf16(ap[mt], bv, oa[mt][nt], 0, 0, 0);
            }
        }

        // O-slice -> LDS Otile
#pragma unroll
        for (int mt = 0; mt < 4; ++mt)
#pragma unroll
            for (int r = 0; r < 4; ++r) {
                const int l = mt * 16 + qd * 4 + r;
                if (l < 49) {
#pragma unroll
                    for (int nt = 0; nt < 2; ++nt)
                        OT[l * OT_STRIDE + h * 32 + nt * 16 + cl] = f2bf(oa[mt][nt][r]);
                }
            }
    }

    __syncthreads();

    // ---------------- Phase B: out = Otile @ w_out^T + bias + x ----------------
    // wave wv covers output cols [wv*96, wv*96+96), rows 0..63 (49 valid)
    const int nbase = wv * 96;
    f32x4 acc[4][6] = {};
#pragma unroll
    for (int kb = 0; kb < 12; ++kb) {
        const int k0 = kb * 32;
        bf16x8 af[4], bw[6];
#pragma unroll
        for (int mt = 0; mt < 4; ++mt)
            af[mt] = *(const bf16x8*)(OT + (mt * 16 + cl) * OT_STRIDE + k0 + qd * 8);
#pragma unroll
        for (int nt = 0; nt < 6; ++nt)
            bw[nt] = *(const bf16x8*)(wout + (size_t)(nbase + nt * 16 + cl) * 384 + k0 + qd * 8);
#pragma unroll
        for (int mt = 0; mt < 4; ++mt)
#pragma unroll
            for (int nt = 0; nt < 6; ++nt)   // swapped: lane cl -> row l, qd*4+r -> col n
                acc[mt][nt] = __builtin_amdgcn_mfma_f32_16x16x32_bf16(bw[nt], af[mt], acc[mt][nt], 0, 0, 0);
    }

    const int b = win >> 6, wh = (win >> 3) & 7, ww = win & 7;
#pragma unroll
    for (int mt = 0; mt < 4; ++mt) {
        const int l = mt * 16 + cl;
        if (l < 49) {
            const int i = l / 7, j = l - i * 7;
            const size_t rowbase = ((size_t)b * 3136 + (wh * 7 + i) * 56 + (ww * 7 + j)) * 384;
#pragma unroll
            for (int nt = 0; nt < 6; ++nt) {
                const int n = nbase + nt * 16 + qd * 4;
                const f32x4 bv = *(const f32x4*)(bias + n);
                const f32x4 xr = *(const f32x4*)(xres + rowbase + n);
                f32x4 o;
#pragma unroll
                for (int r = 0; r < 4; ++r) o[r] = acc[mt][nt][r] + bv[r] + xr[r];
                *(f32x4*)(out + rowbase + n) = o;
            }
        }
    }
}

extern "C" void kernel_launch(void* const* d_in, const int* in_sizes, int n_in,
                              void* d_out, int out_size, void* d_ws, size_t ws_size,
                              hipStream_t stream)
{
    const float* x   = (const float*)d_in[0];
    const float* gam = (const float*)d_in[1];
    const float* bet = (const float*)d_in[2];
    const float* wi  = (const float*)d_in[3];
    const float* bi  = (const float*)d_in[4];
    const float* wo  = (const float*)d_in[5];
    const float* bo  = (const float*)d_in[6];
    float* out = (float*)d_out;

    const int Bb   = in_sizes[0] / (3136 * 384);  // 32
    const int M    = Bb * 3136;                   // 100352 (= NWIN*49)
    const int NWIN = Bb * 64;                     // 2048

    char* ws = (char*)d_ws;
    unsigned short* qw   = (unsigned short*)(ws);                                   // w_in bf16
    unsigned short* ow   = (unsigned short*)(ws + 884736);                          // w_out bf16
    unsigned short* y    = (unsigned short*)(ws + 1179648);                         // [M,384] bf16
    unsigned short* qkv  = (unsigned short*)(ws + 1179648 + (size_t)M * 768);       // [M,1152] bf16

    convw_kernel<<<1728, 256, 0, stream>>>(wi, wo, qw, ow);
    ln_kernel<<<M / 4, 256, 0, stream>>>(x, gam, bet, y);
    gemm_qkv_kernel<<<(M / 128) * 9, 256, 0, stream>>>(y, qw, bi, qkv);
    attn_out_kernel<<<NWIN, 256, 0, stream>>>(qkv, ow, bo, x, out);
}

// Round 6
// 631.844 us; speedup vs baseline: 1.1580x; 1.1580x over previous
//
#include <hip/hip_runtime.h>

typedef __bf16 bf16x8 __attribute__((ext_vector_type(8)));
typedef float f32x4 __attribute__((ext_vector_type(4)));
typedef unsigned short ushort8 __attribute__((ext_vector_type(8)));
typedef unsigned int uu2 __attribute__((ext_vector_type(2)));

#define LDS_AS(p) ((__attribute__((address_space(3))) void*)(p))
#define GLB_AS(p) ((const __attribute__((address_space(1))) void*)(p))

__device__ __forceinline__ unsigned short f2bf(float f) {
    union { float f; unsigned u; } v; v.f = f;
    unsigned r = v.u + 0x7fffu + ((v.u >> 16) & 1u);
    return (unsigned short)(r >> 16);
}

// ---------------- LayerNorm + window partition + bf16 cast (+ weight conv) ----------------
// R6: convw merged in (blocks < 1728 also convert one 256-elem weight chunk)
__global__ __launch_bounds__(256) void ln_kernel(
    const float* __restrict__ x, const float* __restrict__ gam,
    const float* __restrict__ bet, unsigned short* __restrict__ y,
    const float* __restrict__ wi, const float* __restrict__ wo,
    unsigned short* __restrict__ qw, unsigned short* __restrict__ ow)
{
    if (blockIdx.x < 1728) {   // 1728*256 == 1152*384 exactly
        const int i = blockIdx.x * 256 + threadIdx.x;
        qw[i] = f2bf(wi[i]);
        if (i < 384 * 384) ow[i] = f2bf(wo[i]);
    }

    const int lane = threadIdx.x & 63;
    const int wv   = threadIdx.x >> 6;
    const int m    = blockIdx.x * 4 + wv;
    const int win  = m / 49, l = m - win * 49;
    const int b = win >> 6, wh = (win >> 3) & 7, ww = win & 7;
    const int i = l / 7, j = l - i * 7;
    const float2* xr = (const float2*)(x + ((size_t)b * 3136 + (wh * 7 + i) * 56 + (ww * 7 + j)) * 384);

    float2 v[3];
    float s = 0.f, ss = 0.f;
#pragma unroll
    for (int t = 0; t < 3; ++t) {
        v[t] = xr[t * 64 + lane];
        s  += v[t].x + v[t].y;
        ss += v[t].x * v[t].x + v[t].y * v[t].y;
    }
#pragma unroll
    for (int d = 1; d < 64; d <<= 1) {
        s  += __shfl_xor(s, d, 64);
        ss += __shfl_xor(ss, d, 64);
    }
    const float mu  = s * (1.f / 384.f);
    const float var = ss * (1.f / 384.f) - mu * mu;
    const float rs  = rsqrtf(var + 1e-5f);

    unsigned* yr = (unsigned*)(y + (size_t)m * 384);
#pragma unroll
    for (int t = 0; t < 3; ++t) {
        const int c = (t * 64 + lane) * 2;
        float a0 = (v[t].x - mu) * rs * gam[c]     + bet[c];
        float a1 = (v[t].y - mu) * rs * gam[c + 1] + bet[c + 1];
        yr[t * 64 + lane] = (unsigned)f2bf(a0) | ((unsigned)f2bf(a1) << 16);
    }
}

// ---------------- 128x128 bf16 MFMA GEMM, K=384, BK=32 (R2-exact) ----------------
// 3-buffer counted-vmcnt pipeline, T2 LDS swizzle, XCD-chunked grid swizzle,
// swapped-operand MFMA + vectorized epilogue.
template <int N_, int EPI>
__global__ __launch_bounds__(256) void gemm_kernel(
    const unsigned short* __restrict__ A,
    const unsigned short* __restrict__ Bw,
    const float* __restrict__ bias,
    unsigned short* __restrict__ obf,
    const float* __restrict__ xres,
    float* __restrict__ oflt)
{
    __shared__ unsigned short As[3][128 * 32];
    __shared__ unsigned short Bs[3][128 * 32];
    const int lane = threadIdx.x & 63;
    const int wv   = threadIdx.x >> 6;

    const int NB = N_ / 128;
    int sw = blockIdx.x;
    if ((gridDim.x & 7) == 0)
        sw = (sw & 7) * (int)(gridDim.x >> 3) + (sw >> 3);
    const int my = sw / NB;
    const int m0 = my * 128;
    const int n0 = (sw - my * NB) * 128;

    const int wm = (wv & 1) * 64;
    const int wn = (wv >> 1) * 64;
    const int cl = lane & 15;
    const int qd = lane >> 4;
    const int srow = wv * 16 + (lane >> 2);                      // staging row (+t*64)
    const int scol = ((lane & 3) ^ ((lane >> 3) & 3)) * 8;       // swizzled source chunk
    const int rc   = (qd ^ ((cl >> 1) & 3)) * 8;                 // swizzled read chunk

    const unsigned short* gA = A  + (size_t)(m0 + srow) * 384 + scol;
    const unsigned short* gB = Bw + (size_t)(n0 + srow) * 384 + scol;

    f32x4 acc[4][4] = {};

#define STAGE(BUF, KB) do {                                                                                   \
    __builtin_amdgcn_global_load_lds(GLB_AS(gA + (KB) * 32),            LDS_AS(&As[BUF][(wv * 16) * 32]),      16, 0, 0); \
    __builtin_amdgcn_global_load_lds(GLB_AS(gA + 64 * 384 + (KB) * 32), LDS_AS(&As[BUF][(64 + wv * 16) * 32]), 16, 0, 0); \
    __builtin_amdgcn_global_load_lds(GLB_AS(gB + (KB) * 32),            LDS_AS(&Bs[BUF][(wv * 16) * 32]),      16, 0, 0); \
    __builtin_amdgcn_global_load_lds(GLB_AS(gB + 64 * 384 + (KB) * 32), LDS_AS(&Bs[BUF][(64 + wv * 16) * 32]), 16, 0, 0); \
  } while (0)

    STAGE(0, 0);
    STAGE(1, 1);

#pragma unroll
    for (int kb = 0; kb < 12; ++kb) {
        const int cur = kb % 3;
        if (kb < 11) asm volatile("s_waitcnt vmcnt(4)\n\ts_barrier" ::: "memory");
        else         asm volatile("s_waitcnt vmcnt(0)\n\ts_barrier" ::: "memory");

        if (kb < 10) STAGE((kb + 2) % 3, kb + 2);

        bf16x8 af[4], bfr[4];
#pragma unroll
        for (int mt = 0; mt < 4; ++mt)
            af[mt] = *(const bf16x8*)(&As[cur][(wm + mt * 16 + cl) * 32 + rc]);
#pragma unroll
        for (int nt = 0; nt < 4; ++nt)
            bfr[nt] = *(const bf16x8*)(&Bs[cur][(wn + nt * 16 + cl) * 32 + rc]);
#pragma unroll
        for (int mt = 0; mt < 4; ++mt)
#pragma unroll
            for (int nt = 0; nt < 4; ++nt)   // swapped operands: lane cl -> m, qd*4+r -> n
                acc[mt][nt] = __builtin_amdgcn_mfma_f32_16x16x32_bf16(bfr[nt], af[mt], acc[mt][nt], 0, 0, 0);
    }
#undef STAGE

#pragma unroll
    for (int mt = 0; mt < 4; ++mt) {
        const int m = m0 + wm + mt * 16 + cl;
        size_t rowbase = 0;
        if (EPI == 1) {
            const int win = m / 49, l = m - win * 49;
            const int b = win >> 6, wh = (win >> 3) & 7, ww = win & 7;
            const int i = l / 7, j = l - i * 7;
            rowbase = ((size_t)b * 3136 + (wh * 7 + i) * 56 + (ww * 7 + j)) * 384;
        }
#pragma unroll
        for (int nt = 0; nt < 4; ++nt) {
            const int nb = n0 + wn + nt * 16 + qd * 4;
            const f32x4 bv = *(const f32x4*)(bias + nb);
            if (EPI == 0) {
                uu2 p;
                p[0] = (unsigned)f2bf(acc[mt][nt][0] + bv[0]) |
                       ((unsigned)f2bf(acc[mt][nt][1] + bv[1]) << 16);
                p[1] = (unsigned)f2bf(acc[mt][nt][2] + bv[2]) |
                       ((unsigned)f2bf(acc[mt][nt][3] + bv[3]) << 16);
                *(uu2*)(obf + (size_t)m * N_ + nb) = p;
            } else {
                const f32x4 xr = *(const f32x4*)(xres + rowbase + nb);
                f32x4 o;
#pragma unroll
                for (int r = 0; r < 4; ++r) o[r] = acc[mt][nt][r] + bv[r] + xr[r];
                *(f32x4*)(oflt + rowbase + nb) = o;
            }
        }
    }
}

// ---------------- attention: one wave per (window, head) ----------------
// R6: (a) all loads CLAMPED to row 48 instead of exec-guarded: Q-dup rows are
//     discarded by the store guard; K-dup cols are masked to -1e30 before
//     softmax; V-dup rows multiply exactly-zero P columns.
//     (b) V loads hoisted ABOVE softmax (issue-early / consume-late): their
//     HBM latency hides under ~400 cycles of softmax VALU.
__global__ __launch_bounds__(256) void attn_kernel(
    const unsigned short* __restrict__ qkv, unsigned short* __restrict__ o)
{
    __shared__ unsigned short P[4][64 * 72];   // per-wave, stride 72
    const int lane = threadIdx.x & 63;
    const int wv   = threadIdx.x >> 6;
    const int cl = lane & 15;
    const int qd = lane >> 4;
    const int g   = blockIdx.x * 4 + wv;
    const int win = g / 12;
    const int h   = g - win * 12;
    const unsigned short* base = qkv + (size_t)win * (49 * 1152);

    // S = Q @ K^T  (64x64 padded, K=32) -- clamped rows, no branches
    bf16x8 aq[4], bk[4];
#pragma unroll
    for (int mt = 0; mt < 4; ++mt) {
        const int l = mt * 16 + cl;
        const int lc = l < 49 ? l : 48;
        aq[mt] = *(const bf16x8*)(base + (size_t)lc * 1152 + h * 32 + qd * 8);
    }
#pragma unroll
    for (int nt = 0; nt < 4; ++nt) {
        const int lk = nt * 16 + cl;
        const int lc = lk < 49 ? lk : 48;
        bk[nt] = *(const bf16x8*)(base + (size_t)lc * 1152 + 384 + h * 32 + qd * 8);
    }
    f32x4 s[4][4] = {};
#pragma unroll
    for (int mt = 0; mt < 4; ++mt)
#pragma unroll
        for (int nt = 0; nt < 4; ++nt)
            s[mt][nt] = __builtin_amdgcn_mfma_f32_16x16x32_bf16(aq[mt], bk[nt], s[mt][nt], 0, 0, 0);

    // V loads hoisted: issue now, consume after softmax
    const unsigned short* vbase = base + 768 + h * 32;
    bf16x8 bv[2][2];
#pragma unroll
    for (int kk = 0; kk < 2; ++kk)
#pragma unroll
        for (int nt = 0; nt < 2; ++nt) {
            ushort8 tv;
#pragma unroll
            for (int jj = 0; jj < 8; ++jj) {
                const int lk = kk * 32 + qd * 8 + jj;
                const int lc = lk < 49 ? lk : 48;
                tv[jj] = vbase[(size_t)lc * 1152 + nt * 16 + cl];
            }
            bv[kk][nt] = __builtin_bit_cast(bf16x8, tv);
        }

    const float scale = 0.17677669529663687f;   // 1/sqrt(32)
#pragma unroll
    for (int mt = 0; mt < 4; ++mt)
#pragma unroll
        for (int nt = 0; nt < 4; ++nt)
#pragma unroll
            for (int r = 0; r < 4; ++r) {
                float t = s[mt][nt][r] * scale;
                if (nt * 16 + cl >= 49) t = -1e30f;
                s[mt][nt][r] = t;
            }

    // softmax over rows (row lives across lane&15 and the 4 nt-accs)
#pragma unroll
    for (int mt = 0; mt < 4; ++mt)
#pragma unroll
        for (int r = 0; r < 4; ++r) {
            float mx = fmaxf(fmaxf(s[mt][0][r], s[mt][1][r]), fmaxf(s[mt][2][r], s[mt][3][r]));
            mx = fmaxf(mx, __shfl_xor(mx, 1, 64));
            mx = fmaxf(mx, __shfl_xor(mx, 2, 64));
            mx = fmaxf(mx, __shfl_xor(mx, 4, 64));
            mx = fmaxf(mx, __shfl_xor(mx, 8, 64));
            float sm = 0.f;
#pragma unroll
            for (int nt = 0; nt < 4; ++nt) {
                const float p = __expf(s[mt][nt][r] - mx);
                s[mt][nt][r] = p;
                sm += p;
            }
            sm += __shfl_xor(sm, 1, 64);
            sm += __shfl_xor(sm, 2, 64);
            sm += __shfl_xor(sm, 4, 64);
            sm += __shfl_xor(sm, 8, 64);
            const float inv = 1.f / sm;
#pragma unroll
            for (int nt = 0; nt < 4; ++nt)
                s[mt][nt][r] *= inv;
        }

    // P -> LDS (C-layout scatter), read back in A-layout. P[q][k>=49] == 0.
    unsigned short* Pw = &P[wv][0];
#pragma unroll
    for (int mt = 0; mt < 4; ++mt)
#pragma unroll
        for (int nt = 0; nt < 4; ++nt)
#pragma unroll
            for (int r = 0; r < 4; ++r)
                Pw[(mt * 16 + qd * 4 + r) * 72 + nt * 16 + cl] = f2bf(s[mt][nt][r]);

    // O = P @ V   (64x32, K=64)
    f32x4 oa[4][2] = {};
#pragma unroll
    for (int kk = 0; kk < 2; ++kk) {
        bf16x8 ap[4];
#pragma unroll
        for (int mt = 0; mt < 4; ++mt)
            ap[mt] = *(const bf16x8*)(Pw + (mt * 16 + cl) * 72 + kk * 32 + qd * 8);
#pragma unroll
        for (int nt = 0; nt < 2; ++nt)
#pragma unroll
            for (int mt = 0; mt < 4; ++mt)
                oa[mt][nt] = __builtin_amdgcn_mfma_f32_16x16x32_bf16(ap[mt], bv[kk][nt], oa[mt][nt], 0, 0, 0);
    }

    unsigned short* ob = o + (size_t)win * 49 * 384 + h * 32;
#pragma unroll
    for (int mt = 0; mt < 4; ++mt)
#pragma unroll
        for (int r = 0; r < 4; ++r) {
            const int l = mt * 16 + qd * 4 + r;
            if (l < 49) {
#pragma unroll
                for (int nt = 0; nt < 2; ++nt)
                    ob[(size_t)l * 384 + nt * 16 + cl] = f2bf(oa[mt][nt][r]);
            }
        }
}

extern "C" void kernel_launch(void* const* d_in, const int* in_sizes, int n_in,
                              void* d_out, int out_size, void* d_ws, size_t ws_size,
                              hipStream_t stream)
{
    const float* x   = (const float*)d_in[0];
    const float* gam = (const float*)d_in[1];
    const float* bet = (const float*)d_in[2];
    const float* wi  = (const float*)d_in[3];
    const float* bi  = (const float*)d_in[4];
    const float* wo  = (const float*)d_in[5];
    const float* bo  = (const float*)d_in[6];
    float* out = (float*)d_out;

    const int Bb   = in_sizes[0] / (3136 * 384);  // 32
    const int M    = Bb * 3136;                   // 100352 (= NWIN*49)
    const int NWIN = Bb * 64;                     // 2048

    char* ws = (char*)d_ws;
    unsigned short* qw   = (unsigned short*)(ws);                                   // w_in bf16
    unsigned short* ow   = (unsigned short*)(ws + 884736);                          // w_out bf16
    unsigned short* y    = (unsigned short*)(ws + 1179648);                         // [M,384] bf16
    unsigned short* qkv  = (unsigned short*)(ws + 1179648 + (size_t)M * 768);       // [M,1152] bf16
    unsigned short* owin = (unsigned short*)(ws + 1179648 + (size_t)M * 768 + (size_t)M * 2304); // [M,384] bf16

    ln_kernel<<<M / 4, 256, 0, stream>>>(x, gam, bet, y, wi, wo, qw, ow);
    gemm_kernel<1152, 0><<<(M / 128) * 9, 256, 0, stream>>>(y, qw, bi, qkv, nullptr, nullptr);
    attn_kernel<<<NWIN * 12 / 4, 256, 0, stream>>>(qkv, owin);
    gemm_kernel<384, 1><<<(M / 128) * 3, 256, 0, stream>>>(owin, ow, bo, nullptr, x, out);
}